// Round 25
// baseline (516.655 us; speedup 1.0000x reference)
//
#include <hip/hip_runtime.h>
#include <hip/hip_bf16.h>

// ProteinGNNTransformer — round 25: attention QB 128->256, FOUR q-sets per wave
// (r22->r23 A/B showed ILP-amortization beats occupancy here: 1->2 sets cut
// 81.4->77.3us despite occupancy 33->18%). Shared V-stage/K-loads/barrier/V-reads
// now amortized 4x. Grid (16,8,4)=512 blocks = 8 waves/CU = the 2-waves/SIMD
// VGPR cap (est ~190 regs). Everything else identical to r24 (465.6us).

#define NPROT 3000
#define NAA   25
#define NPROP 1071
#define NTOT  4096
#define DIM   256
#define NH    8
#define DHD   32
#define FFD   1024
#define NEDGE 131072
#define LNEPS 1e-5f
#define KSPLIT 4
#define KVQ (NTOT/KSPLIT)

typedef unsigned short u16;
typedef unsigned int u32;
typedef __attribute__((ext_vector_type(8))) short short8v;
typedef __attribute__((ext_vector_type(4))) float float4v;
typedef __attribute__((ext_vector_type(2))) unsigned int uint2v;

__device__ __forceinline__ u16 f2bu(float x){
  union { __hip_bfloat16 h; u16 u; } c; c.h = __float2bfloat16(x); return c.u;
}
__device__ __forceinline__ float bu2f(u16 u){
  union { u32 i; float f; } c; c.i = ((u32)u) << 16; return c.f;
}
__device__ __forceinline__ float4v mfma16(short8v a, short8v b, float4v c){
  return __builtin_amdgcn_mfma_f32_16x16x32_bf16(a, b, c, 0, 0, 0);
}
// pack two f32 to two bf16 (truncation) — v_perm idiom
__device__ __forceinline__ u32 packbf(float lo, float hi){
  u32 ul = __builtin_bit_cast(u32, lo);
  u32 uh = __builtin_bit_cast(u32, hi);
  return (ul >> 16) | (uh & 0xFFFF0000u);
}
// async global->LDS, 16 bytes/lane (dest = wave-uniform base + lane*16)
__device__ __forceinline__ void gload_lds16(const u16* g, u16* l){
  __builtin_amdgcn_global_load_lds(
      (const __attribute__((address_space(1))) void*)g,
      (__attribute__((address_space(3))) void*)l, 16, 0, 0);
}

// ---------------- embedding concat (+bf16 shadow of cur) ----------------
__global__ __launch_bounds__(256) void k_embed(const float* __restrict__ pe, const float* __restrict__ ae,
                                               const float* __restrict__ qe,
                                               float* __restrict__ cur, float* __restrict__ tot,
                                               u16* __restrict__ curb){
  int i = blockIdx.x*256 + threadIdx.x;
  int row = i >> 8;
  float v;
  if (row < NPROT)           v = pe[i];
  else if (row < NPROT+NAA)  v = ae[i - NPROT*DIM];
  else                       v = qe[i - (NPROT+NAA)*DIM];
  cur[i] = v; tot[i] = v; curb[i] = f2bu(v);
}

__global__ __launch_bounds__(256) void k_zero(int* __restrict__ p, int n){
  int i = blockIdx.x*256 + threadIdx.x; if (i < n) p[i] = 0;
}

// ---------------- fused weight transpose+convert ----------------
__global__ __launch_bounds__(256) void k_wconv_all(const float* __restrict__ Wqkv, const float* __restrict__ Wo,
                                                   const float* __restrict__ W1, const float* __restrict__ W2,
                                                   u16* __restrict__ wqkvt, u16* __restrict__ wot,
                                                   u16* __restrict__ w1t, u16* __restrict__ w2t){
  int b = blockIdx.x;
  const float* W; u16* Wt; int K, N, n;
  if (b < 768)       { W = Wqkv; Wt = wqkvt; K = 256;  N = 768;  n = b; }
  else if (b < 1024) { W = Wo;   Wt = wot;   K = 256;  N = 256;  n = b - 768; }
  else if (b < 2048) { W = W1;   Wt = w1t;   K = 256;  N = 1024; n = b - 1024; }
  else               { W = W2;   Wt = w2t;   K = 1024; N = 256;  n = b - 2048; }
  for (int k = threadIdx.x; k < K; k += 256)
    Wt[(size_t)n*K + k] = f2bu(W[(size_t)k*N + n]);
}

// ---------------- CSR build ----------------
__global__ __launch_bounds__(256) void k_hist(const int* __restrict__ rows, int* __restrict__ cnt){
  int e = blockIdx.x*256 + threadIdx.x; if (e < NEDGE) atomicAdd(&cnt[rows[e]], 1);
}

__global__ __launch_bounds__(64) void k_scan(const int* __restrict__ cnt, int* __restrict__ rowptr,
                                             int* __restrict__ cursor){
  int lane = threadIdx.x;
  int sum = 0;
  for (int i = 0; i < 64; ++i) sum += cnt[lane*64 + i];
  int pref = sum;
  #pragma unroll
  for (int off = 1; off < 64; off <<= 1){
    int u = __shfl_up(pref, off);
    if (lane >= off) pref += u;
  }
  int run = pref - sum;
  for (int i = 0; i < 64; ++i){
    int c = cnt[lane*64 + i];
    rowptr[lane*64 + i] = run;
    cursor[lane*64 + i] = run;
    run += c;
  }
  if (lane == 63) rowptr[NTOT] = run;
}

__global__ __launch_bounds__(256) void k_scatter(const int* __restrict__ rows, const int* __restrict__ cols,
                                                 const float* __restrict__ vals, int* __restrict__ cursor,
                                                 int* __restrict__ ccol, float* __restrict__ cval){
  int e = blockIdx.x*256 + threadIdx.x; if (e >= NEDGE) return;
  int p = atomicAdd(&cursor[rows[e]], 1);
  ccol[p] = cols[e]; cval[p] = vals[e];
}

// ---------------- SpMM (bf16 gather): f32 out + bf16 shadow ----------------
__global__ __launch_bounds__(256) void k_spmm(const int* __restrict__ rowptr, const int* __restrict__ ccol,
                                              const float* __restrict__ cval, const u16* __restrict__ xb,
                                              float* __restrict__ out, u16* __restrict__ outb){
  int r = blockIdx.x, c = threadIdx.x;
  int s = rowptr[r], e = rowptr[r+1];
  float acc = 0.f;
  for (int i = s; i < e; ++i)
    acc += cval[i] * bu2f(xb[((size_t)ccol[i] << 8) + c]);
  out[((size_t)r << 8) + c] = acc;
  outb[((size_t)r << 8) + c] = f2bu(acc);
}

// ---------------- MFMA GEMM, 64x64 tile; async staging ----------------
template<int RELU, int BIAS, int BF16OUT>
__global__ __launch_bounds__(256) void k_gemm64(const u16* __restrict__ A, const u16* __restrict__ Wt,
                                                const float* __restrict__ bias, void* __restrict__ Cv,
                                                int M, int K, int Nc){
  __shared__ u16 Al[64*64];
  __shared__ u16 Bl[64*64];
  const int tid = threadIdx.x;
  const int w  = tid >> 6, l = tid & 63, lr = l & 15, g = l >> 4;
  const int row0 = blockIdx.y*64, col0 = blockIdx.x*64;
  const int wm = (w >> 1)*32, wn = (w & 1)*32;
  const int srow = (l >> 3);
  const int soct = (l & 7) ^ srow;
  float4v acc[2][2] = {};

  for (int k0 = 0; k0 < K; k0 += 64){
    #pragma unroll
    for (int i = 0; i < 2; ++i){
      int row = 16*w + 8*i + srow;
      gload_lds16(A  + (size_t)(row0 + row)*K + k0 + soct*8, Al + (16*w + 8*i)*64);
      gload_lds16(Wt + (size_t)(col0 + row)*K + k0 + soct*8, Bl + (16*w + 8*i)*64);
    }
    __syncthreads();
    #pragma unroll
    for (int kk = 0; kk < 2; ++kk){
      short8v af[2], bfr[2];
      #pragma unroll
      for (int i = 0; i < 2; ++i){
        int am = wm + 16*i + lr;
        af[i]  = *(const short8v*)(Al + am*64 + (((4*kk + g) ^ (am & 7))*8));
        int bn = wn + 16*i + lr;
        bfr[i] = *(const short8v*)(Bl + bn*64 + (((4*kk + g) ^ (bn & 7))*8));
      }
      acc[0][0] = mfma16(af[0], bfr[0], acc[0][0]);
      acc[0][1] = mfma16(af[0], bfr[1], acc[0][1]);
      acc[1][0] = mfma16(af[1], bfr[0], acc[1][0]);
      acc[1][1] = mfma16(af[1], bfr[1], acc[1][1]);
    }
    __syncthreads();
  }

  #pragma unroll
  for (int mi = 0; mi < 2; ++mi){
    #pragma unroll
    for (int ni = 0; ni < 2; ++ni){
      int col = col0 + wn + 16*ni + lr;
      float bv = BIAS ? bias[col] : 0.f;
      #pragma unroll
      for (int j = 0; j < 4; ++j){
        int row = row0 + wm + 16*mi + 4*g + j;
        float v = acc[mi][ni][j] + bv;
        if (RELU) v = fmaxf(v, 0.f);
        if (BF16OUT) ((u16*)Cv)[(size_t)row*Nc + col] = f2bu(v);
        else         ((float*)Cv)[(size_t)row*Nc + col] = v;
      }
    }
  }
}

// ---------------- MFMA flash attention: Q-block 256 (4 q-sets/wave), split-K x4 ----------------
__global__ __launch_bounds__(256) void k_attn_mfma(const u16* __restrict__ qbf,
                                                   u16* __restrict__ p0, u16* __restrict__ p1,
                                                   u16* __restrict__ p2, u16* __restrict__ p3,
                                                   float* __restrict__ mbuf, float* __restrict__ lbuf){
  __shared__ u16 Vt[2][32*64];
  __shared__ u16 Pl[4][16*64];
  __shared__ float Fl[4][16];
  const int h   = blockIdx.y;
  const int ks  = blockIdx.z;
  const int qb  = blockIdx.x * 256;
  const int tid = threadIdx.x;
  const int w   = tid >> 6;
  const int l   = tid & 63;
  const int lr  = l & 15;
  const int g   = l >> 4;
  const int sr  = tid >> 2;
  const int sq  = tid & 3;
  const float SC  = 0.17677669529663687f;          // 1/sqrt(32)
  const float SCL = 0.25503837f;                    // SC * log2(e)
  const float DEFER = 31.368f;                      // 8/SCL: P bounded by 2^8
  u16* opart = (ks == 0) ? p0 : (ks == 1) ? p1 : (ks == 2) ? p2 : p3;

  short8v qf[4];
  #pragma unroll
  for (int ss = 0; ss < 4; ++ss)
    qf[ss] = *(const short8v*)(qbf + (size_t)(qb + 64*ss + 16*w + lr)*768 + h*DHD + 8*g);
  short8v ones;
  #pragma unroll
  for (int j = 0; j < 8; ++j) ones[j] = (short)0x3F80;   // bf16 1.0

  float4v oa0[4], oa1[4], accl[4];
  float mrun[4];
  #pragma unroll
  for (int ss = 0; ss < 4; ++ss){
    oa0[ss] = (float4v){0,0,0,0};
    oa1[ss] = (float4v){0,0,0,0};
    accl[ss] = (float4v){0,0,0,0};
    mrun[ss] = -1e30f;
  }
  u16* pw = &Pl[w][0];

  const u16* vp = qbf + (size_t)(ks*KVQ + sr)*768 + 512 + h*DHD + 8*sq;
  const u16* kp = qbf + (size_t)(ks*KVQ + lr)*768 + 256 + h*DHD + 8*g;
  short8v vreg = *(const short8v*)vp;
  short8v kf0 = *(const short8v*)(kp);
  short8v kf1 = *(const short8v*)(kp + (size_t)16*768);
  short8v kf2 = *(const short8v*)(kp + (size_t)32*768);
  short8v kf3 = *(const short8v*)(kp + (size_t)48*768);

  const int gh = g >> 1, gl = 4*(g & 1);
  const int slotp0 = (0 + g) ^ (lr & 7);
  const int slotp1 = (4 + g) ^ (lr & 7);

  const int NIT = KVQ/64;
  for (int t = 0; t < NIT; ++t){
    u16* vt = &Vt[t & 1][0];
    #pragma unroll
    for (int j = 0; j < 8; ++j){
      int row  = 8*sq + j;
      int slot = (sr >> 3) ^ j;
      vt[row*64 + slot*8 + (sr & 7)] = (u16)vreg[j];
    }
    __syncthreads();
    vp += (size_t)64*768;
    vreg = *(const short8v*)vp;            // branchless prefetch (bounded overread)

    // ---- QK^T for all 4 q-sets with the same K frags (16 MFMA) ----
    float4v sv[4][4];
    #pragma unroll
    for (int ss = 0; ss < 4; ++ss){
      sv[ss][0] = mfma16(kf0, qf[ss], (float4v){0,0,0,0});
      sv[ss][1] = mfma16(kf1, qf[ss], (float4v){0,0,0,0});
      sv[ss][2] = mfma16(kf2, qf[ss], (float4v){0,0,0,0});
      sv[ss][3] = mfma16(kf3, qf[ss], (float4v){0,0,0,0});
    }
    kp += (size_t)64*768;
    kf0 = *(const short8v*)(kp);
    kf1 = *(const short8v*)(kp + (size_t)16*768);
    kf2 = *(const short8v*)(kp + (size_t)32*768);
    kf3 = *(const short8v*)(kp + (size_t)48*768);

    // ---- hoist V frags once (shared by all 4 PV sets) ----
    short8v v00 = *(const short8v*)(vt + lr*64      + slotp0*8);
    short8v v10 = *(const short8v*)(vt + (lr+16)*64 + slotp0*8);
    short8v v01 = *(const short8v*)(vt + lr*64      + slotp1*8);
    short8v v11 = *(const short8v*)(vt + (lr+16)*64 + slotp1*8);

    // ---- per-set softmax + PV (sets sequential; Pl reused) ----
    #pragma unroll
    for (int ss = 0; ss < 4; ++ss){
      float m0 = fmaxf(fmaxf(fmaxf(sv[ss][0][0],sv[ss][0][1]),sv[ss][0][2]),sv[ss][0][3]);
      float m1 = fmaxf(fmaxf(fmaxf(sv[ss][1][0],sv[ss][1][1]),sv[ss][1][2]),sv[ss][1][3]);
      float m2 = fmaxf(fmaxf(fmaxf(sv[ss][2][0],sv[ss][2][1]),sv[ss][2][2]),sv[ss][2][3]);
      float m3 = fmaxf(fmaxf(fmaxf(sv[ss][3][0],sv[ss][3][1]),sv[ss][3][2]),sv[ss][3][3]);
      float tm = fmaxf(fmaxf(fmaxf(m0,m1),m2),m3);
      tm = fmaxf(tm, __shfl_xor(tm, 16));
      tm = fmaxf(tm, __shfl_xor(tm, 32));
      const bool nomax = __all(tm <= mrun[ss] + DEFER);
      float fac = 1.f;
      if (!nomax){
        float mn = fmaxf(mrun[ss], tm);
        fac = exp2f((mrun[ss] - mn)*SCL);
        mrun[ss] = mn;
      }
      float mns = mrun[ss]*SCL;
      #pragma unroll
      for (int i = 0; i < 4; ++i){
        sv[ss][i][0] = exp2f(__builtin_fmaf(sv[ss][i][0], SCL, -mns));
        sv[ss][i][1] = exp2f(__builtin_fmaf(sv[ss][i][1], SCL, -mns));
        sv[ss][i][2] = exp2f(__builtin_fmaf(sv[ss][i][2], SCL, -mns));
        sv[ss][i][3] = exp2f(__builtin_fmaf(sv[ss][i][3], SCL, -mns));
      }
      uint2v* d0 = (uint2v*)(pw + lr*64 + ((0 + gh) ^ (lr & 7))*8 + gl);
      uint2v* d1 = (uint2v*)(pw + lr*64 + ((2 + gh) ^ (lr & 7))*8 + gl);
      uint2v* d2 = (uint2v*)(pw + lr*64 + ((4 + gh) ^ (lr & 7))*8 + gl);
      uint2v* d3 = (uint2v*)(pw + lr*64 + ((6 + gh) ^ (lr & 7))*8 + gl);
      *d0 = (uint2v){packbf(sv[ss][0][0],sv[ss][0][1]), packbf(sv[ss][0][2],sv[ss][0][3])};
      *d1 = (uint2v){packbf(sv[ss][1][0],sv[ss][1][1]), packbf(sv[ss][1][2],sv[ss][1][3])};
      *d2 = (uint2v){packbf(sv[ss][2][0],sv[ss][2][1]), packbf(sv[ss][2][2],sv[ss][2][3])};
      *d3 = (uint2v){packbf(sv[ss][3][0],sv[ss][3][1]), packbf(sv[ss][3][2],sv[ss][3][3])};
      if (!nomax){
        if (g == 0) Fl[w][lr] = fac;
        float fq0 = Fl[w][4*g+0], fq1 = Fl[w][4*g+1], fq2 = Fl[w][4*g+2], fq3 = Fl[w][4*g+3];
        oa0[ss][0]*=fq0; oa0[ss][1]*=fq1; oa0[ss][2]*=fq2; oa0[ss][3]*=fq3;
        oa1[ss][0]*=fq0; oa1[ss][1]*=fq1; oa1[ss][2]*=fq2; oa1[ss][3]*=fq3;
        accl[ss][0]*=fq0; accl[ss][1]*=fq1; accl[ss][2]*=fq2; accl[ss][3]*=fq3;
      }
      short8v pa0 = *(const short8v*)(pw + lr*64 + slotp0*8);
      short8v pa1 = *(const short8v*)(pw + lr*64 + slotp1*8);
      oa0[ss]  = mfma16(pa0, v00, oa0[ss]);
      oa1[ss]  = mfma16(pa0, v10, oa1[ss]);
      accl[ss] = mfma16(pa0, ones, accl[ss]);
      oa0[ss]  = mfma16(pa1, v01, oa0[ss]);
      oa1[ss]  = mfma16(pa1, v11, oa1[ss]);
      accl[ss] = mfma16(pa1, ones, accl[ss]);
    }
  }

  // ---- epilogue: bf16 unnormalized partials + scaled m + l (all sets) ----
  #pragma unroll
  for (int ss = 0; ss < 4; ++ss){
    #pragma unroll
    for (int j = 0; j < 4; ++j){
      size_t row = (size_t)(qb + 64*ss + 16*w + 4*g + j);
      opart[row*DIM + h*DHD + lr]      = f2bu(oa0[ss][j]);
      opart[row*DIM + h*DHD + 16 + lr] = f2bu(oa1[ss][j]);
    }
  }
  if (l < 16){
    #pragma unroll
    for (int ss = 0; ss < 4; ++ss){
      size_t mi = (size_t)(ks*NH + h)*NTOT + qb + 64*ss + 16*w + lr;
      mbuf[mi] = mrun[ss]*SC;
    }
  }
  if (lr == 0){
    #pragma unroll
    for (int ss = 0; ss < 4; ++ss){
      #pragma unroll
      for (int j = 0; j < 4; ++j){
        size_t mi = (size_t)(ks*NH + h)*NTOT + qb + 64*ss + 16*w + 4*g + j;
        lbuf[mi] = accl[ss][j];
      }
    }
  }
}

// ---------------- split-K merge (4-way, standalone) ----------------
__global__ __launch_bounds__(256) void k_attn_merge4(const u16* __restrict__ p0, const u16* __restrict__ p1,
                                                     const u16* __restrict__ p2, const u16* __restrict__ p3,
                                                     const float* __restrict__ mbuf, const float* __restrict__ lbuf,
                                                     u16* __restrict__ obf){
  int i = blockIdx.x*256 + threadIdx.x;
  int r = i >> 8, c = i & 255, h = c >> 5;
  float m0 = mbuf[(size_t)(0*NH + h)*NTOT + r];
  float m1 = mbuf[(size_t)(1*NH + h)*NTOT + r];
  float m2 = mbuf[(size_t)(2*NH + h)*NTOT + r];
  float m3 = mbuf[(size_t)(3*NH + h)*NTOT + r];
  float M = fmaxf(fmaxf(m0, m1), fmaxf(m2, m3));
  float e0 = __expf(m0 - M), e1 = __expf(m1 - M);
  float e2 = __expf(m2 - M), e3 = __expf(m3 - M);
  float L = e0*lbuf[(size_t)(0*NH + h)*NTOT + r] + e1*lbuf[(size_t)(1*NH + h)*NTOT + r]
          + e2*lbuf[(size_t)(2*NH + h)*NTOT + r] + e3*lbuf[(size_t)(3*NH + h)*NTOT + r];
  float acc = e0*bu2f(p0[i]) + e1*bu2f(p1[i]) + e2*bu2f(p2[i]) + e3*bu2f(p3[i]);
  obf[i] = f2bu(acc / L);
}

// ---------------- fused residual + LayerNorm (+bf16 shadow) ----------------
template<int DUAL>
__global__ __launch_bounds__(256) void k_add_ln(const float* __restrict__ a, const float* __restrict__ b,
                                                const float* __restrict__ g, const float* __restrict__ be,
                                                float* __restrict__ out, u16* __restrict__ out2){
  __shared__ float red[4];
  int r = blockIdx.x, c = threadIdx.x;
  float v = a[((size_t)r << 8) + c] + b[((size_t)r << 8) + c];
  float s = v;
  #pragma unroll
  for (int off = 32; off; off >>= 1) s += __shfl_down(s, off);
  if ((c & 63) == 0) red[c >> 6] = s;
  __syncthreads();
  float mean = (red[0]+red[1]+red[2]+red[3]) * (1.f/DIM);
  __syncthreads();
  float d = v - mean;
  float s2 = d*d;
  #pragma unroll
  for (int off = 32; off; off >>= 1) s2 += __shfl_down(s2, off);
  if ((c & 63) == 0) red[c >> 6] = s2;
  __syncthreads();
  float var = (red[0]+red[1]+red[2]+red[3]) * (1.f/DIM);
  float rv = d * rsqrtf(var + LNEPS) * g[c] + be[c];
  out[((size_t)r << 8) + c] = rv;
  if (DUAL) out2[((size_t)r << 8) + c] = f2bu(rv);
}

// ---------------- fused LN2 + update (+bf16 cur shadow, +final output) ----------------
template<int FINAL>
__global__ __launch_bounds__(256) void k_add_ln_upd(const float* __restrict__ a, const float* __restrict__ b,
                                                    const float* __restrict__ g, const float* __restrict__ be,
                                                    float* __restrict__ cur, float* __restrict__ tot,
                                                    u16* __restrict__ curb, float* __restrict__ out){
  __shared__ float red[4];
  int r = blockIdx.x, c = threadIdx.x;
  size_t idx = ((size_t)r << 8) + c;
  float v = a[idx] + b[idx];
  float s = v;
  #pragma unroll
  for (int off = 32; off; off >>= 1) s += __shfl_down(s, off);
  if ((c & 63) == 0) red[c >> 6] = s;
  __syncthreads();
  float mean = (red[0]+red[1]+red[2]+red[3]) * (1.f/DIM);
  __syncthreads();
  float d = v - mean;
  float s2 = d*d;
  #pragma unroll
  for (int off = 32; off; off >>= 1) s2 += __shfl_down(s2, off);
  if ((c & 63) == 0) red[c >> 6] = s2;
  __syncthreads();
  float var = (red[0]+red[1]+red[2]+red[3]) * (1.f/DIM);
  float rv = d * rsqrtf(var + LNEPS) * g[c] + be[c];
  float cu = cur[idx] + rv;
  cur[idx] = cu;
  if (!FINAL) curb[idx] = f2bu(cu);
  float tv = tot[idx] + cu;
  tot[idx] = tv;
  if (FINAL){
    out[idx] = tv;
    out[(size_t)NTOT*DIM + idx] = tv;
  }
}

extern "C" void kernel_launch(void* const* d_in, const int* in_sizes, int n_in,
                              void* d_out, int out_size, void* d_ws, size_t ws_size,
                              hipStream_t stream){
  const int*   adj_row = (const int*)  d_in[0];
  const int*   adj_col = (const int*)  d_in[1];
  const float* adj_val = (const float*)d_in[2];
  const float* pe   = (const float*)d_in[3];
  const float* ae   = (const float*)d_in[4];
  const float* qe   = (const float*)d_in[5];
  const float* Wqkv = (const float*)d_in[6];
  const float* Wo   = (const float*)d_in[7];
  const float* W1   = (const float*)d_in[8];
  const float* b1   = (const float*)d_in[9];
  const float* W2   = (const float*)d_in[10];
  const float* b2   = (const float*)d_in[11];
  const float* g1   = (const float*)d_in[12];
  const float* be1  = (const float*)d_in[13];
  const float* g2   = (const float*)d_in[14];
  const float* be2  = (const float*)d_in[15];
  float* out = (float*)d_out;

  // ---- workspace (~36.7 MB, layout unchanged) ----
  char* w = (char*)d_ws;
  float* cur  = (float*)w; w += (size_t)NTOT*DIM*4;
  float* tot  = (float*)w; w += (size_t)NTOT*DIM*4;
  float* tf   = (float*)w; w += (size_t)NTOT*DIM*4;
  float* pbuf = (float*)w; w += (size_t)NTOT*DIM*4;        // proj/ffn2 out
  float* x1   = (float*)w; w += (size_t)NTOT*DIM*4;        // x1; attn partials 0-1 during attn
  u16* tbf    = (u16*)w;   w += (size_t)NTOT*DIM*2;        // spmm bf16; attn m/l
  u16* curb   = (u16*)w;   w += (size_t)NTOT*DIM*2;        // bf16 cur shadow; attn partial 3
  u16* x1b    = (u16*)w;   w += (size_t)NTOT*DIM*2;        // x1 bf16; attn partial 2
  u16* hq     = (u16*)w;   w += (size_t)NTOT*FFD*2;        // qbf ∪ h ∪ obf
  u16* wqkvt  = (u16*)w;   w += (size_t)768*256*2;
  u16* wot    = (u16*)w;   w += (size_t)256*256*2;
  u16* w1t    = (u16*)w;   w += (size_t)1024*256*2;
  u16* w2t    = (u16*)w;   w += (size_t)256*1024*2;
  int* rowptr = (int*)w;   w += (size_t)(NTOT+1)*4;
  int* cnt    = (int*)w;   w += (size_t)NTOT*4;
  int* cursor = (int*)w;   w += (size_t)NTOT*4;
  int* ccol   = (int*)w;   w += (size_t)NEDGE*4;
  float* cval = (float*)w; w += (size_t)NEDGE*4;
  u16* qbf = hq;
  u16* obf = hq;                                // merge output overwrites dead qkv (2 MB)
  u16* pp0 = (u16*)x1;                          // partial 0 (2 MB)
  u16* pp1 = (u16*)x1 + (size_t)NTOT*DIM;       // partial 1 (2 MB)
  u16* pp2 = x1b;                               // partial 2
  u16* pp3 = curb;                              // partial 3 (curb dead during attn)
  float* mbuf = (float*)tbf;                    // [KSPLIT][NH][NTOT] f32 (512 KB)
  float* lbuf = mbuf + (size_t)KSPLIT*NH*NTOT;  // 512 KB (inside dead tbf)

  k_zero<<<16, 256, 0, stream>>>(cnt, NTOT);
  k_embed<<<NTOT, 256, 0, stream>>>(pe, ae, qe, cur, tot, curb);
  k_hist<<<NEDGE/256, 256, 0, stream>>>(adj_row, cnt);
  k_scan<<<1, 64, 0, stream>>>(cnt, rowptr, cursor);
  k_scatter<<<NEDGE/256, 256, 0, stream>>>(adj_row, adj_col, adj_val, cursor, ccol, cval);
  k_wconv_all<<<2304, 256, 0, stream>>>(Wqkv, Wo, W1, W2, wqkvt, wot, w1t, w2t);

  for (int blk = 0; blk < 3; ++blk){
    k_spmm<<<NTOT, 256, 0, stream>>>(rowptr, ccol, cval, curb, tf, tbf);
    k_gemm64<0,0,1><<<dim3(768/64, NTOT/64), 256, 0, stream>>>(tbf, wqkvt, nullptr, qbf, NTOT, 256, 768);
    k_attn_mfma<<<dim3(NTOT/256, NH, KSPLIT), 256, 0, stream>>>(qbf, pp0, pp1, pp2, pp3, mbuf, lbuf);
    k_attn_merge4<<<NTOT*DIM/256, 256, 0, stream>>>(pp0, pp1, pp2, pp3, mbuf, lbuf, obf);
    k_gemm64<0,0,0><<<dim3(256/64, NTOT/64), 256, 0, stream>>>(obf, wot, nullptr, pbuf, NTOT, 256, 256);
    k_add_ln<1><<<NTOT, 256, 0, stream>>>(tf, pbuf, g1, be1, x1, x1b);
    k_gemm64<1,1,1><<<dim3(1024/64, NTOT/64), 256, 0, stream>>>(x1b, w1t, b1, hq, NTOT, 256, 1024);
    k_gemm64<0,1,0><<<dim3(256/64, NTOT/64), 256, 0, stream>>>(hq, w2t, b2, pbuf, NTOT, 1024, 256);
    if (blk < 2)
      k_add_ln_upd<0><<<NTOT, 256, 0, stream>>>(x1, pbuf, g2, be2, cur, tot, curb, nullptr);
    else
      k_add_ln_upd<1><<<NTOT, 256, 0, stream>>>(x1, pbuf, g2, be2, cur, tot, nullptr, out);
  }
}

// Round 26
// 463.831 us; speedup vs baseline: 1.1139x; 1.1139x over previous
//
#include <hip/hip_runtime.h>
#include <hip/hip_bf16.h>

// ProteinGNNTransformer — round 26: FINAL — clean revert to r24 (best verified:
// 465.6us). r25's 4-q-set variant hit VGPR 156 / occupancy 10.7% and regressed
// (attn 77->94.8us): the ILP-amortization curve is non-monotonic, 2 sets is the
// optimum. r24 config: QB=128 (2 q-sets/wave), KSPLIT=4, standalone 4-way merge,
// async-staged 64^2 GEMMs, fused LN/update, bf16 spmm gather.

#define NPROT 3000
#define NAA   25
#define NPROP 1071
#define NTOT  4096
#define DIM   256
#define NH    8
#define DHD   32
#define FFD   1024
#define NEDGE 131072
#define LNEPS 1e-5f
#define KSPLIT 4
#define KVQ (NTOT/KSPLIT)

typedef unsigned short u16;
typedef unsigned int u32;
typedef __attribute__((ext_vector_type(8))) short short8v;
typedef __attribute__((ext_vector_type(4))) float float4v;
typedef __attribute__((ext_vector_type(2))) unsigned int uint2v;

__device__ __forceinline__ u16 f2bu(float x){
  union { __hip_bfloat16 h; u16 u; } c; c.h = __float2bfloat16(x); return c.u;
}
__device__ __forceinline__ float bu2f(u16 u){
  union { u32 i; float f; } c; c.i = ((u32)u) << 16; return c.f;
}
__device__ __forceinline__ float4v mfma16(short8v a, short8v b, float4v c){
  return __builtin_amdgcn_mfma_f32_16x16x32_bf16(a, b, c, 0, 0, 0);
}
// pack two f32 to two bf16 (truncation) — v_perm idiom
__device__ __forceinline__ u32 packbf(float lo, float hi){
  u32 ul = __builtin_bit_cast(u32, lo);
  u32 uh = __builtin_bit_cast(u32, hi);
  return (ul >> 16) | (uh & 0xFFFF0000u);
}
// async global->LDS, 16 bytes/lane (dest = wave-uniform base + lane*16)
__device__ __forceinline__ void gload_lds16(const u16* g, u16* l){
  __builtin_amdgcn_global_load_lds(
      (const __attribute__((address_space(1))) void*)g,
      (__attribute__((address_space(3))) void*)l, 16, 0, 0);
}

// ---------------- embedding concat (+bf16 shadow of cur) ----------------
__global__ __launch_bounds__(256) void k_embed(const float* __restrict__ pe, const float* __restrict__ ae,
                                               const float* __restrict__ qe,
                                               float* __restrict__ cur, float* __restrict__ tot,
                                               u16* __restrict__ curb){
  int i = blockIdx.x*256 + threadIdx.x;
  int row = i >> 8;
  float v;
  if (row < NPROT)           v = pe[i];
  else if (row < NPROT+NAA)  v = ae[i - NPROT*DIM];
  else                       v = qe[i - (NPROT+NAA)*DIM];
  cur[i] = v; tot[i] = v; curb[i] = f2bu(v);
}

__global__ __launch_bounds__(256) void k_zero(int* __restrict__ p, int n){
  int i = blockIdx.x*256 + threadIdx.x; if (i < n) p[i] = 0;
}

// ---------------- fused weight transpose+convert ----------------
__global__ __launch_bounds__(256) void k_wconv_all(const float* __restrict__ Wqkv, const float* __restrict__ Wo,
                                                   const float* __restrict__ W1, const float* __restrict__ W2,
                                                   u16* __restrict__ wqkvt, u16* __restrict__ wot,
                                                   u16* __restrict__ w1t, u16* __restrict__ w2t){
  int b = blockIdx.x;
  const float* W; u16* Wt; int K, N, n;
  if (b < 768)       { W = Wqkv; Wt = wqkvt; K = 256;  N = 768;  n = b; }
  else if (b < 1024) { W = Wo;   Wt = wot;   K = 256;  N = 256;  n = b - 768; }
  else if (b < 2048) { W = W1;   Wt = w1t;   K = 256;  N = 1024; n = b - 1024; }
  else               { W = W2;   Wt = w2t;   K = 1024; N = 256;  n = b - 2048; }
  for (int k = threadIdx.x; k < K; k += 256)
    Wt[(size_t)n*K + k] = f2bu(W[(size_t)k*N + n]);
}

// ---------------- CSR build ----------------
__global__ __launch_bounds__(256) void k_hist(const int* __restrict__ rows, int* __restrict__ cnt){
  int e = blockIdx.x*256 + threadIdx.x; if (e < NEDGE) atomicAdd(&cnt[rows[e]], 1);
}

__global__ __launch_bounds__(64) void k_scan(const int* __restrict__ cnt, int* __restrict__ rowptr,
                                             int* __restrict__ cursor){
  int lane = threadIdx.x;
  int sum = 0;
  for (int i = 0; i < 64; ++i) sum += cnt[lane*64 + i];
  int pref = sum;
  #pragma unroll
  for (int off = 1; off < 64; off <<= 1){
    int u = __shfl_up(pref, off);
    if (lane >= off) pref += u;
  }
  int run = pref - sum;
  for (int i = 0; i < 64; ++i){
    int c = cnt[lane*64 + i];
    rowptr[lane*64 + i] = run;
    cursor[lane*64 + i] = run;
    run += c;
  }
  if (lane == 63) rowptr[NTOT] = run;
}

__global__ __launch_bounds__(256) void k_scatter(const int* __restrict__ rows, const int* __restrict__ cols,
                                                 const float* __restrict__ vals, int* __restrict__ cursor,
                                                 int* __restrict__ ccol, float* __restrict__ cval){
  int e = blockIdx.x*256 + threadIdx.x; if (e >= NEDGE) return;
  int p = atomicAdd(&cursor[rows[e]], 1);
  ccol[p] = cols[e]; cval[p] = vals[e];
}

// ---------------- SpMM (bf16 gather): f32 out + bf16 shadow ----------------
__global__ __launch_bounds__(256) void k_spmm(const int* __restrict__ rowptr, const int* __restrict__ ccol,
                                              const float* __restrict__ cval, const u16* __restrict__ xb,
                                              float* __restrict__ out, u16* __restrict__ outb){
  int r = blockIdx.x, c = threadIdx.x;
  int s = rowptr[r], e = rowptr[r+1];
  float acc = 0.f;
  for (int i = s; i < e; ++i)
    acc += cval[i] * bu2f(xb[((size_t)ccol[i] << 8) + c]);
  out[((size_t)r << 8) + c] = acc;
  outb[((size_t)r << 8) + c] = f2bu(acc);
}

// ---------------- MFMA GEMM, 64x64 tile; async staging ----------------
template<int RELU, int BIAS, int BF16OUT>
__global__ __launch_bounds__(256) void k_gemm64(const u16* __restrict__ A, const u16* __restrict__ Wt,
                                                const float* __restrict__ bias, void* __restrict__ Cv,
                                                int M, int K, int Nc){
  __shared__ u16 Al[64*64];
  __shared__ u16 Bl[64*64];
  const int tid = threadIdx.x;
  const int w  = tid >> 6, l = tid & 63, lr = l & 15, g = l >> 4;
  const int row0 = blockIdx.y*64, col0 = blockIdx.x*64;
  const int wm = (w >> 1)*32, wn = (w & 1)*32;
  const int srow = (l >> 3);
  const int soct = (l & 7) ^ srow;
  float4v acc[2][2] = {};

  for (int k0 = 0; k0 < K; k0 += 64){
    #pragma unroll
    for (int i = 0; i < 2; ++i){
      int row = 16*w + 8*i + srow;
      gload_lds16(A  + (size_t)(row0 + row)*K + k0 + soct*8, Al + (16*w + 8*i)*64);
      gload_lds16(Wt + (size_t)(col0 + row)*K + k0 + soct*8, Bl + (16*w + 8*i)*64);
    }
    __syncthreads();
    #pragma unroll
    for (int kk = 0; kk < 2; ++kk){
      short8v af[2], bfr[2];
      #pragma unroll
      for (int i = 0; i < 2; ++i){
        int am = wm + 16*i + lr;
        af[i]  = *(const short8v*)(Al + am*64 + (((4*kk + g) ^ (am & 7))*8));
        int bn = wn + 16*i + lr;
        bfr[i] = *(const short8v*)(Bl + bn*64 + (((4*kk + g) ^ (bn & 7))*8));
      }
      acc[0][0] = mfma16(af[0], bfr[0], acc[0][0]);
      acc[0][1] = mfma16(af[0], bfr[1], acc[0][1]);
      acc[1][0] = mfma16(af[1], bfr[0], acc[1][0]);
      acc[1][1] = mfma16(af[1], bfr[1], acc[1][1]);
    }
    __syncthreads();
  }

  #pragma unroll
  for (int mi = 0; mi < 2; ++mi){
    #pragma unroll
    for (int ni = 0; ni < 2; ++ni){
      int col = col0 + wn + 16*ni + lr;
      float bv = BIAS ? bias[col] : 0.f;
      #pragma unroll
      for (int j = 0; j < 4; ++j){
        int row = row0 + wm + 16*mi + 4*g + j;
        float v = acc[mi][ni][j] + bv;
        if (RELU) v = fmaxf(v, 0.f);
        if (BF16OUT) ((u16*)Cv)[(size_t)row*Nc + col] = f2bu(v);
        else         ((float*)Cv)[(size_t)row*Nc + col] = v;
      }
    }
  }
}

// ---------------- MFMA flash attention: Q-block 128 (2 q-sets/wave), split-K x4 ----------------
__global__ __launch_bounds__(256) void k_attn_mfma(const u16* __restrict__ qbf,
                                                   u16* __restrict__ p0, u16* __restrict__ p1,
                                                   u16* __restrict__ p2, u16* __restrict__ p3,
                                                   float* __restrict__ mbuf, float* __restrict__ lbuf){
  __shared__ u16 Vt[2][32*64];
  __shared__ u16 Pl[4][16*64];
  __shared__ float Fl[4][16];
  const int h   = blockIdx.y;
  const int ks  = blockIdx.z;
  const int qb  = blockIdx.x * 128;
  const int tid = threadIdx.x;
  const int w   = tid >> 6;
  const int l   = tid & 63;
  const int lr  = l & 15;
  const int g   = l >> 4;
  const int sr  = tid >> 2;
  const int sq  = tid & 3;
  const float SC  = 0.17677669529663687f;          // 1/sqrt(32)
  const float SCL = 0.25503837f;                    // SC * log2(e)
  const float DEFER = 31.368f;                      // 8/SCL: P bounded by 2^8
  u16* opart = (ks == 0) ? p0 : (ks == 1) ? p1 : (ks == 2) ? p2 : p3;

  short8v qfA = *(const short8v*)(qbf + (size_t)(qb + 16*w + lr)*768 + h*DHD + 8*g);
  short8v qfB = *(const short8v*)(qbf + (size_t)(qb + 64 + 16*w + lr)*768 + h*DHD + 8*g);
  short8v ones;
  #pragma unroll
  for (int j = 0; j < 8; ++j) ones[j] = (short)0x3F80;   // bf16 1.0

  float4v oaA0 = {0,0,0,0}, oaA1 = {0,0,0,0}, acclA = {0,0,0,0};
  float4v oaB0 = {0,0,0,0}, oaB1 = {0,0,0,0}, acclB = {0,0,0,0};
  float mrunA = -1e30f, mrunB = -1e30f;
  u16* pw = &Pl[w][0];

  const u16* vp = qbf + (size_t)(ks*KVQ + sr)*768 + 512 + h*DHD + 8*sq;
  const u16* kp = qbf + (size_t)(ks*KVQ + lr)*768 + 256 + h*DHD + 8*g;
  short8v vreg = *(const short8v*)vp;
  short8v kf0 = *(const short8v*)(kp);
  short8v kf1 = *(const short8v*)(kp + (size_t)16*768);
  short8v kf2 = *(const short8v*)(kp + (size_t)32*768);
  short8v kf3 = *(const short8v*)(kp + (size_t)48*768);

  const int gh = g >> 1, gl = 4*(g & 1);
  const int slotp0 = (0 + g) ^ (lr & 7);
  const int slotp1 = (4 + g) ^ (lr & 7);

  const int NIT = KVQ/64;
  for (int t = 0; t < NIT; ++t){
    u16* vt = &Vt[t & 1][0];
    #pragma unroll
    for (int j = 0; j < 8; ++j){
      int row  = 8*sq + j;
      int slot = (sr >> 3) ^ j;
      vt[row*64 + slot*8 + (sr & 7)] = (u16)vreg[j];
    }
    __syncthreads();
    vp += (size_t)64*768;
    vreg = *(const short8v*)vp;            // branchless prefetch (bounded overread)

    // ---- QK^T for BOTH q-sets with the same K frags ----
    float4v sA0 = mfma16(kf0, qfA, (float4v){0,0,0,0});
    float4v sA1 = mfma16(kf1, qfA, (float4v){0,0,0,0});
    float4v sA2 = mfma16(kf2, qfA, (float4v){0,0,0,0});
    float4v sA3 = mfma16(kf3, qfA, (float4v){0,0,0,0});
    float4v sB0 = mfma16(kf0, qfB, (float4v){0,0,0,0});
    float4v sB1 = mfma16(kf1, qfB, (float4v){0,0,0,0});
    float4v sB2 = mfma16(kf2, qfB, (float4v){0,0,0,0});
    float4v sB3 = mfma16(kf3, qfB, (float4v){0,0,0,0});
    kp += (size_t)64*768;
    kf0 = *(const short8v*)(kp);
    kf1 = *(const short8v*)(kp + (size_t)16*768);
    kf2 = *(const short8v*)(kp + (size_t)32*768);
    kf3 = *(const short8v*)(kp + (size_t)48*768);

    // ---- hoist V frags once (shared by both PV sets) ----
    short8v v00 = *(const short8v*)(vt + lr*64      + slotp0*8);
    short8v v10 = *(const short8v*)(vt + (lr+16)*64 + slotp0*8);
    short8v v01 = *(const short8v*)(vt + lr*64      + slotp1*8);
    short8v v11 = *(const short8v*)(vt + (lr+16)*64 + slotp1*8);

    // ================= set A =================
    {
      float m0 = fmaxf(fmaxf(fmaxf(sA0[0],sA0[1]),sA0[2]),sA0[3]);
      float m1 = fmaxf(fmaxf(fmaxf(sA1[0],sA1[1]),sA1[2]),sA1[3]);
      float m2 = fmaxf(fmaxf(fmaxf(sA2[0],sA2[1]),sA2[2]),sA2[3]);
      float m3 = fmaxf(fmaxf(fmaxf(sA3[0],sA3[1]),sA3[2]),sA3[3]);
      float tm = fmaxf(fmaxf(fmaxf(m0,m1),m2),m3);
      tm = fmaxf(tm, __shfl_xor(tm, 16));
      tm = fmaxf(tm, __shfl_xor(tm, 32));
      const bool nomax = __all(tm <= mrunA + DEFER);
      float fac = 1.f;
      if (!nomax){
        float mn = fmaxf(mrunA, tm);
        fac = exp2f((mrunA - mn)*SCL);
        mrunA = mn;
      }
      float mns = mrunA*SCL;
      #pragma unroll
      for (int j = 0; j < 4; ++j){
        sA0[j] = exp2f(__builtin_fmaf(sA0[j], SCL, -mns));
        sA1[j] = exp2f(__builtin_fmaf(sA1[j], SCL, -mns));
        sA2[j] = exp2f(__builtin_fmaf(sA2[j], SCL, -mns));
        sA3[j] = exp2f(__builtin_fmaf(sA3[j], SCL, -mns));
      }
      uint2v* d0 = (uint2v*)(pw + lr*64 + ((0 + gh) ^ (lr & 7))*8 + gl);
      uint2v* d1 = (uint2v*)(pw + lr*64 + ((2 + gh) ^ (lr & 7))*8 + gl);
      uint2v* d2 = (uint2v*)(pw + lr*64 + ((4 + gh) ^ (lr & 7))*8 + gl);
      uint2v* d3 = (uint2v*)(pw + lr*64 + ((6 + gh) ^ (lr & 7))*8 + gl);
      *d0 = (uint2v){packbf(sA0[0],sA0[1]), packbf(sA0[2],sA0[3])};
      *d1 = (uint2v){packbf(sA1[0],sA1[1]), packbf(sA1[2],sA1[3])};
      *d2 = (uint2v){packbf(sA2[0],sA2[1]), packbf(sA2[2],sA2[3])};
      *d3 = (uint2v){packbf(sA3[0],sA3[1]), packbf(sA3[2],sA3[3])};
      if (!nomax){
        if (g == 0) Fl[w][lr] = fac;
        float fq0 = Fl[w][4*g+0], fq1 = Fl[w][4*g+1], fq2 = Fl[w][4*g+2], fq3 = Fl[w][4*g+3];
        oaA0[0]*=fq0; oaA0[1]*=fq1; oaA0[2]*=fq2; oaA0[3]*=fq3;
        oaA1[0]*=fq0; oaA1[1]*=fq1; oaA1[2]*=fq2; oaA1[3]*=fq3;
        acclA[0]*=fq0; acclA[1]*=fq1; acclA[2]*=fq2; acclA[3]*=fq3;
      }
      short8v pa0 = *(const short8v*)(pw + lr*64 + slotp0*8);
      short8v pa1 = *(const short8v*)(pw + lr*64 + slotp1*8);
      oaA0  = mfma16(pa0, v00, oaA0);
      oaA1  = mfma16(pa0, v10, oaA1);
      acclA = mfma16(pa0, ones, acclA);
      oaA0  = mfma16(pa1, v01, oaA0);
      oaA1  = mfma16(pa1, v11, oaA1);
      acclA = mfma16(pa1, ones, acclA);
    }
    // ================= set B =================
    {
      float m0 = fmaxf(fmaxf(fmaxf(sB0[0],sB0[1]),sB0[2]),sB0[3]);
      float m1 = fmaxf(fmaxf(fmaxf(sB1[0],sB1[1]),sB1[2]),sB1[3]);
      float m2 = fmaxf(fmaxf(fmaxf(sB2[0],sB2[1]),sB2[2]),sB2[3]);
      float m3 = fmaxf(fmaxf(fmaxf(sB3[0],sB3[1]),sB3[2]),sB3[3]);
      float tm = fmaxf(fmaxf(fmaxf(m0,m1),m2),m3);
      tm = fmaxf(tm, __shfl_xor(tm, 16));
      tm = fmaxf(tm, __shfl_xor(tm, 32));
      const bool nomax = __all(tm <= mrunB + DEFER);
      float fac = 1.f;
      if (!nomax){
        float mn = fmaxf(mrunB, tm);
        fac = exp2f((mrunB - mn)*SCL);
        mrunB = mn;
      }
      float mns = mrunB*SCL;
      #pragma unroll
      for (int j = 0; j < 4; ++j){
        sB0[j] = exp2f(__builtin_fmaf(sB0[j], SCL, -mns));
        sB1[j] = exp2f(__builtin_fmaf(sB1[j], SCL, -mns));
        sB2[j] = exp2f(__builtin_fmaf(sB2[j], SCL, -mns));
        sB3[j] = exp2f(__builtin_fmaf(sB3[j], SCL, -mns));
      }
      uint2v* d0 = (uint2v*)(pw + lr*64 + ((0 + gh) ^ (lr & 7))*8 + gl);
      uint2v* d1 = (uint2v*)(pw + lr*64 + ((2 + gh) ^ (lr & 7))*8 + gl);
      uint2v* d2 = (uint2v*)(pw + lr*64 + ((4 + gh) ^ (lr & 7))*8 + gl);
      uint2v* d3 = (uint2v*)(pw + lr*64 + ((6 + gh) ^ (lr & 7))*8 + gl);
      *d0 = (uint2v){packbf(sB0[0],sB0[1]), packbf(sB0[2],sB0[3])};
      *d1 = (uint2v){packbf(sB1[0],sB1[1]), packbf(sB1[2],sB1[3])};
      *d2 = (uint2v){packbf(sB2[0],sB2[1]), packbf(sB2[2],sB2[3])};
      *d3 = (uint2v){packbf(sB3[0],sB3[1]), packbf(sB3[2],sB3[3])};
      if (!nomax){
        if (g == 0) Fl[w][lr] = fac;
        float fq0 = Fl[w][4*g+0], fq1 = Fl[w][4*g+1], fq2 = Fl[w][4*g+2], fq3 = Fl[w][4*g+3];
        oaB0[0]*=fq0; oaB0[1]*=fq1; oaB0[2]*=fq2; oaB0[3]*=fq3;
        oaB1[0]*=fq0; oaB1[1]*=fq1; oaB1[2]*=fq2; oaB1[3]*=fq3;
        acclB[0]*=fq0; acclB[1]*=fq1; acclB[2]*=fq2; acclB[3]*=fq3;
      }
      short8v pa0 = *(const short8v*)(pw + lr*64 + slotp0*8);
      short8v pa1 = *(const short8v*)(pw + lr*64 + slotp1*8);
      oaB0  = mfma16(pa0, v00, oaB0);
      oaB1  = mfma16(pa0, v10, oaB1);
      acclB = mfma16(pa0, ones, acclB);
      oaB0  = mfma16(pa1, v01, oaB0);
      oaB1  = mfma16(pa1, v11, oaB1);
      acclB = mfma16(pa1, ones, acclB);
    }
  }

  // ---- epilogue: bf16 unnormalized partials + scaled m + l (both sets) ----
  #pragma unroll
  for (int j = 0; j < 4; ++j){
    size_t rowA = (size_t)(qb + 16*w + 4*g + j);
    size_t rowB = rowA + 64;
    opart[rowA*DIM + h*DHD + lr]      = f2bu(oaA0[j]);
    opart[rowA*DIM + h*DHD + 16 + lr] = f2bu(oaA1[j]);
    opart[rowB*DIM + h*DHD + lr]      = f2bu(oaB0[j]);
    opart[rowB*DIM + h*DHD + 16 + lr] = f2bu(oaB1[j]);
  }
  if (l < 16){
    size_t miA = (size_t)(ks*NH + h)*NTOT + qb + 16*w + lr;
    mbuf[miA]      = mrunA*SC;
    mbuf[miA + 64] = mrunB*SC;
  }
  if (lr == 0){
    #pragma unroll
    for (int j = 0; j < 4; ++j){
      size_t miA = (size_t)(ks*NH + h)*NTOT + qb + 16*w + 4*g + j;
      lbuf[miA]      = acclA[j];
      lbuf[miA + 64] = acclB[j];
    }
  }
}

// ---------------- split-K merge (4-way, standalone, computed once) ----------------
__global__ __launch_bounds__(256) void k_attn_merge4(const u16* __restrict__ p0, const u16* __restrict__ p1,
                                                     const u16* __restrict__ p2, const u16* __restrict__ p3,
                                                     const float* __restrict__ mbuf, const float* __restrict__ lbuf,
                                                     u16* __restrict__ obf){
  int i = blockIdx.x*256 + threadIdx.x;
  int r = i >> 8, c = i & 255, h = c >> 5;
  float m0 = mbuf[(size_t)(0*NH + h)*NTOT + r];
  float m1 = mbuf[(size_t)(1*NH + h)*NTOT + r];
  float m2 = mbuf[(size_t)(2*NH + h)*NTOT + r];
  float m3 = mbuf[(size_t)(3*NH + h)*NTOT + r];
  float M = fmaxf(fmaxf(m0, m1), fmaxf(m2, m3));
  float e0 = __expf(m0 - M), e1 = __expf(m1 - M);
  float e2 = __expf(m2 - M), e3 = __expf(m3 - M);
  float L = e0*lbuf[(size_t)(0*NH + h)*NTOT + r] + e1*lbuf[(size_t)(1*NH + h)*NTOT + r]
          + e2*lbuf[(size_t)(2*NH + h)*NTOT + r] + e3*lbuf[(size_t)(3*NH + h)*NTOT + r];
  float acc = e0*bu2f(p0[i]) + e1*bu2f(p1[i]) + e2*bu2f(p2[i]) + e3*bu2f(p3[i]);
  obf[i] = f2bu(acc / L);
}

// ---------------- fused residual + LayerNorm (+bf16 shadow) ----------------
template<int DUAL>
__global__ __launch_bounds__(256) void k_add_ln(const float* __restrict__ a, const float* __restrict__ b,
                                                const float* __restrict__ g, const float* __restrict__ be,
                                                float* __restrict__ out, u16* __restrict__ out2){
  __shared__ float red[4];
  int r = blockIdx.x, c = threadIdx.x;
  float v = a[((size_t)r << 8) + c] + b[((size_t)r << 8) + c];
  float s = v;
  #pragma unroll
  for (int off = 32; off; off >>= 1) s += __shfl_down(s, off);
  if ((c & 63) == 0) red[c >> 6] = s;
  __syncthreads();
  float mean = (red[0]+red[1]+red[2]+red[3]) * (1.f/DIM);
  __syncthreads();
  float d = v - mean;
  float s2 = d*d;
  #pragma unroll
  for (int off = 32; off; off >>= 1) s2 += __shfl_down(s2, off);
  if ((c & 63) == 0) red[c >> 6] = s2;
  __syncthreads();
  float var = (red[0]+red[1]+red[2]+red[3]) * (1.f/DIM);
  float rv = d * rsqrtf(var + LNEPS) * g[c] + be[c];
  out[((size_t)r << 8) + c] = rv;
  if (DUAL) out2[((size_t)r << 8) + c] = f2bu(rv);
}

// ---------------- fused LN2 + update (+bf16 cur shadow, +final output) ----------------
template<int FINAL>
__global__ __launch_bounds__(256) void k_add_ln_upd(const float* __restrict__ a, const float* __restrict__ b,
                                                    const float* __restrict__ g, const float* __restrict__ be,
                                                    float* __restrict__ cur, float* __restrict__ tot,
                                                    u16* __restrict__ curb, float* __restrict__ out){
  __shared__ float red[4];
  int r = blockIdx.x, c = threadIdx.x;
  size_t idx = ((size_t)r << 8) + c;
  float v = a[idx] + b[idx];
  float s = v;
  #pragma unroll
  for (int off = 32; off; off >>= 1) s += __shfl_down(s, off);
  if ((c & 63) == 0) red[c >> 6] = s;
  __syncthreads();
  float mean = (red[0]+red[1]+red[2]+red[3]) * (1.f/DIM);
  __syncthreads();
  float d = v - mean;
  float s2 = d*d;
  #pragma unroll
  for (int off = 32; off; off >>= 1) s2 += __shfl_down(s2, off);
  if ((c & 63) == 0) red[c >> 6] = s2;
  __syncthreads();
  float var = (red[0]+red[1]+red[2]+red[3]) * (1.f/DIM);
  float rv = d * rsqrtf(var + LNEPS) * g[c] + be[c];
  float cu = cur[idx] + rv;
  cur[idx] = cu;
  if (!FINAL) curb[idx] = f2bu(cu);
  float tv = tot[idx] + cu;
  tot[idx] = tv;
  if (FINAL){
    out[idx] = tv;
    out[(size_t)NTOT*DIM + idx] = tv;
  }
}

extern "C" void kernel_launch(void* const* d_in, const int* in_sizes, int n_in,
                              void* d_out, int out_size, void* d_ws, size_t ws_size,
                              hipStream_t stream){
  const int*   adj_row = (const int*)  d_in[0];
  const int*   adj_col = (const int*)  d_in[1];
  const float* adj_val = (const float*)d_in[2];
  const float* pe   = (const float*)d_in[3];
  const float* ae   = (const float*)d_in[4];
  const float* qe   = (const float*)d_in[5];
  const float* Wqkv = (const float*)d_in[6];
  const float* Wo   = (const float*)d_in[7];
  const float* W1   = (const float*)d_in[8];
  const float* b1   = (const float*)d_in[9];
  const float* W2   = (const float*)d_in[10];
  const float* b2   = (const float*)d_in[11];
  const float* g1   = (const float*)d_in[12];
  const float* be1  = (const float*)d_in[13];
  const float* g2   = (const float*)d_in[14];
  const float* be2  = (const float*)d_in[15];
  float* out = (float*)d_out;

  // ---- workspace (~36.7 MB, layout unchanged) ----
  char* w = (char*)d_ws;
  float* cur  = (float*)w; w += (size_t)NTOT*DIM*4;
  float* tot  = (float*)w; w += (size_t)NTOT*DIM*4;
  float* tf   = (float*)w; w += (size_t)NTOT*DIM*4;
  float* pbuf = (float*)w; w += (size_t)NTOT*DIM*4;        // proj/ffn2 out
  float* x1   = (float*)w; w += (size_t)NTOT*DIM*4;        // x1; attn partials 0-1 during attn
  u16* tbf    = (u16*)w;   w += (size_t)NTOT*DIM*2;        // spmm bf16; attn m/l
  u16* curb   = (u16*)w;   w += (size_t)NTOT*DIM*2;        // bf16 cur shadow; attn partial 3
  u16* x1b    = (u16*)w;   w += (size_t)NTOT*DIM*2;        // x1 bf16; attn partial 2
  u16* hq     = (u16*)w;   w += (size_t)NTOT*FFD*2;        // qbf ∪ h ∪ obf
  u16* wqkvt  = (u16*)w;   w += (size_t)768*256*2;
  u16* wot    = (u16*)w;   w += (size_t)256*256*2;
  u16* w1t    = (u16*)w;   w += (size_t)1024*256*2;
  u16* w2t    = (u16*)w;   w += (size_t)256*1024*2;
  int* rowptr = (int*)w;   w += (size_t)(NTOT+1)*4;
  int* cnt    = (int*)w;   w += (size_t)NTOT*4;
  int* cursor = (int*)w;   w += (size_t)NTOT*4;
  int* ccol   = (int*)w;   w += (size_t)NEDGE*4;
  float* cval = (float*)w; w += (size_t)NEDGE*4;
  u16* qbf = hq;
  u16* obf = hq;                                // merge output overwrites dead qkv (2 MB)
  u16* pp0 = (u16*)x1;                          // partial 0 (2 MB)
  u16* pp1 = (u16*)x1 + (size_t)NTOT*DIM;       // partial 1 (2 MB)
  u16* pp2 = x1b;                               // partial 2
  u16* pp3 = curb;                              // partial 3 (curb dead during attn)
  float* mbuf = (float*)tbf;                    // [KSPLIT][NH][NTOT] f32 (512 KB)
  float* lbuf = mbuf + (size_t)KSPLIT*NH*NTOT;  // 512 KB (inside dead tbf)

  k_zero<<<16, 256, 0, stream>>>(cnt, NTOT);
  k_embed<<<NTOT, 256, 0, stream>>>(pe, ae, qe, cur, tot, curb);
  k_hist<<<NEDGE/256, 256, 0, stream>>>(adj_row, cnt);
  k_scan<<<1, 64, 0, stream>>>(cnt, rowptr, cursor);
  k_scatter<<<NEDGE/256, 256, 0, stream>>>(adj_row, adj_col, adj_val, cursor, ccol, cval);
  k_wconv_all<<<2304, 256, 0, stream>>>(Wqkv, Wo, W1, W2, wqkvt, wot, w1t, w2t);

  for (int blk = 0; blk < 3; ++blk){
    k_spmm<<<NTOT, 256, 0, stream>>>(rowptr, ccol, cval, curb, tf, tbf);
    k_gemm64<0,0,1><<<dim3(768/64, NTOT/64), 256, 0, stream>>>(tbf, wqkvt, nullptr, qbf, NTOT, 256, 768);
    k_attn_mfma<<<dim3(NTOT/128, NH, KSPLIT), 256, 0, stream>>>(qbf, pp0, pp1, pp2, pp3, mbuf, lbuf);
    k_attn_merge4<<<NTOT*DIM/256, 256, 0, stream>>>(pp0, pp1, pp2, pp3, mbuf, lbuf, obf);
    k_gemm64<0,0,0><<<dim3(256/64, NTOT/64), 256, 0, stream>>>(obf, wot, nullptr, pbuf, NTOT, 256, 256);
    k_add_ln<1><<<NTOT, 256, 0, stream>>>(tf, pbuf, g1, be1, x1, x1b);
    k_gemm64<1,1,1><<<dim3(1024/64, NTOT/64), 256, 0, stream>>>(x1b, w1t, b1, hq, NTOT, 256, 1024);
    k_gemm64<0,1,0><<<dim3(256/64, NTOT/64), 256, 0, stream>>>(hq, w2t, b2, pbuf, NTOT, 1024, 256);
    if (blk < 2)
      k_add_ln_upd<0><<<NTOT, 256, 0, stream>>>(x1, pbuf, g2, be2, cur, tot, curb, nullptr);
    else
      k_add_ln_upd<1><<<NTOT, 256, 0, stream>>>(x1, pbuf, g2, be2, cur, tot, nullptr, out);
  }
}